// Round 5
// baseline (968.805 us; speedup 1.0000x reference)
//
#include <hip/hip_runtime.h>
#include <hip/hip_fp16.h>
#include <cmath>

// ---------------------------------------------------------------------------
// Self_Attention: B=8, C=256, C_=32, H=W=64, N=4096, GAMMA=1.0
// R5: pass2 latency attack. Grid x2 via j-split (8 blocks/CU, atomicAdd
// partial-O into x-preloaded out), LOG2E folded into ft + shift dropped
// (P = exp2(S')*linv: one exp + one mul per element), pass1 ILP-2.
// ws: xt 16M | wf 256K | ft 2M | gt 2M | hm 16M | linv 128K
// ---------------------------------------------------------------------------

#define BN 8
#define CC 256
#define CQ 32
#define NN 4096

typedef _Float16 half8 __attribute__((ext_vector_type(8)));
typedef _Float16 half4v __attribute__((ext_vector_type(4)));
typedef float f32x4 __attribute__((ext_vector_type(4)));

static __device__ __forceinline__ float fexp2(float x) {
    return __builtin_amdgcn_exp2f(x);
}

#define LOG2E 1.44269504f

// --------------------------------------------------------------------------
// K0: weight conversion f32 -> f16. 8192 + 8192 + 65536 = 81920 elements.
// --------------------------------------------------------------------------
__global__ __launch_bounds__(256) void cvtw_kernel(
    const float* __restrict__ fw, const float* __restrict__ gw,
    const float* __restrict__ hw, __half* __restrict__ wf16)
{
    int i = blockIdx.x * 256 + threadIdx.x;
    float v;
    if (i < 8192)       v = fw[i];
    else if (i < 16384) v = gw[i - 8192];
    else                v = hw[i - 16384];
    wf16[i] = __float2half(v);
}

// --------------------------------------------------------------------------
// K1: transpose + cvt x[b][c][n] f32 -> xt[b][n][c] f16.  64n x 64c tiles.
// --------------------------------------------------------------------------
__global__ __launch_bounds__(256) void transpose_kernel(
    const float* __restrict__ x, __half* __restrict__ xt)
{
    const int gid = blockIdx.x;
    const int b = gid & 7, rest = gid >> 3;
    const int n0 = (rest & 63) * 64;
    const int c0 = (rest >> 6) * 64;
    const int tid = threadIdx.x;

    __shared__ float T[64 * 65];

    const float* xb = x + ((size_t)b * CC + c0) * NN + n0;
    const int u  = tid >> 4;          // 0..15
    const int n4 = (tid & 15) * 4;
#pragma unroll
    for (int r = 0; r < 4; ++r) {
        int c = r * 16 + u;
        f32x4 v = __builtin_nontemporal_load((const f32x4*)(xb + (size_t)c * NN + n4));
        T[c * 65 + n4 + 0] = v.x;
        T[c * 65 + n4 + 1] = v.y;
        T[c * 65 + n4 + 2] = v.z;
        T[c * 65 + n4 + 3] = v.w;
    }
    __syncthreads();

    const int lane = tid & 63, w = tid >> 6;
    const int n  = w * 16 + (lane >> 2);
    const int cc = (lane & 3) * 16;
    half8 o0, o1;
#pragma unroll
    for (int k = 0; k < 8; ++k) {
        o0[k] = (_Float16)T[(cc + k) * 65 + n];
        o1[k] = (_Float16)T[(cc + 8 + k) * 65 + n];
    }
    __half* dst = xt + ((size_t)b * NN + n0 + n) * CC + c0 + cc;
    *(half8*)(void*)dst = o0;
    *(half8*)(void*)(dst + 8) = o1;
}

// --------------------------------------------------------------------------
// K2: MFMA projections. 1D grid 2560: b = gid&7, then (nt 0..63, ot 0..4).
//   ot==0: f+g.  f rows scaled by LOG2E (folds softmax's log2e into S').
//   ot>=1: h.    hm[c][n] b64 stores.
// --------------------------------------------------------------------------
__global__ __launch_bounds__(256) void proj_kernel(
    const __half* __restrict__ xt, const __half* __restrict__ wf16,
    const float* __restrict__ fb, const float* __restrict__ gb,
    const float* __restrict__ hb,
    __half* __restrict__ ft, __half* __restrict__ gt, __half* __restrict__ hm)
{
    const int tid = threadIdx.x;
    const int w = tid >> 6, lane = tid & 63, col = lane & 15, q = lane >> 4;
    const int gid = blockIdx.x;
    const int b = gid & 7, rest = gid >> 3;
    const int n0 = (rest & 63) * 64;
    const int ot = rest >> 6;          // 0..4

    const __half* xtb  = xt + (size_t)b * NN * CC;
    const __half* fw16 = wf16;
    const __half* gw16 = wf16 + 8192;
    const __half* hw16 = wf16 + 16384;

    f32x4 acc[4];
#pragma unroll
    for (int mt = 0; mt < 4; ++mt) acc[mt] = (f32x4){0.f, 0.f, 0.f, 0.f};

    if (ot == 0) {
        const int pix = n0 + 16 * w + col;
#pragma unroll
        for (int ks = 0; ks < 8; ++ks) {
            half8 bf = *(const half8*)(const void*)(xtb + (size_t)pix * CC + ks * 32 + q * 8);
#pragma unroll
            for (int mt = 0; mt < 4; ++mt) {
                const __half* wp = (mt < 2) ? (fw16 + (16 * mt + col) * CC)
                                            : (gw16 + (16 * (mt - 2) + col) * CC);
                half8 af = *(const half8*)(const void*)(wp + ks * 32 + q * 8);
                acc[mt] = __builtin_amdgcn_mfma_f32_16x16x32_f16(af, bf, acc[mt], 0, 0, 0);
            }
        }
#pragma unroll
        for (int mt = 0; mt < 4; ++mt) {
            const int mtl = mt & 1;
            const float* bsel = (mt < 2) ? fb : gb;
            const float scale = (mt < 2) ? LOG2E : 1.0f;   // fold log2e into f
            __half* dsel = (mt < 2) ? ft : gt;
            half4v hv;
#pragma unroll
            for (int r = 0; r < 4; ++r)
                hv[r] = (_Float16)((acc[mt][r] + bsel[16 * mtl + 4 * q + r]) * scale);
            *(half4v*)(void*)(dsel + ((size_t)b * NN + pix) * CQ + 16 * mtl + 4 * q) = hv;
        }
    } else {
        const int c = (ot - 1) * 64 + 16 * w + col;
#pragma unroll
        for (int ks = 0; ks < 8; ++ks) {
            half8 bf = *(const half8*)(const void*)(hw16 + (size_t)c * CC + ks * 32 + q * 8);
#pragma unroll
            for (int mt = 0; mt < 4; ++mt) {
                half8 af = *(const half8*)(const void*)(xtb + (size_t)(n0 + 16 * mt + col) * CC + ks * 32 + q * 8);
                acc[mt] = __builtin_amdgcn_mfma_f32_16x16x32_f16(af, bf, acc[mt], 0, 0, 0);
            }
        }
        const float bias = hb[c];
#pragma unroll
        for (int mt = 0; mt < 4; ++mt) {
            half4v hv;
#pragma unroll
            for (int r = 0; r < 4; ++r)
                hv[r] = (_Float16)(acc[mt][r] + bias);
            *(half4v*)(void*)(hm + ((size_t)b * CC + c) * NN + n0 + 16 * mt + 4 * q) = hv;
        }
    }
}

// --------------------------------------------------------------------------
// K3: per-column softmax denominator, unshifted (S' = log2e*S via scaled ft;
// exp2 sums stay in fp32 range: max term ~2^58, sum <= 2^70):
// linv[b][j] = 1 / sum_i exp2(S'_ij).  ILP-2: two independent MFMA->exp
// chains (i, i+16) per iter.  1D grid 512: b = gid&7.
// --------------------------------------------------------------------------
__global__ __launch_bounds__(256) void pass1_kernel(
    const __half* __restrict__ ft, const __half* __restrict__ gt,
    float* __restrict__ linv)
{
    const int tid = threadIdx.x;
    const int w = tid >> 6, lane = tid & 63, col = lane & 15, q = lane >> 4;
    const int gid = blockIdx.x;
    const int b = gid & 7;
    const int jg = (gid >> 3) * 64 + 16 * w + col;

    const __half* fbase = ft + (size_t)b * NN * CQ;
    half8 gfrag = *(const half8*)(const void*)(gt + ((size_t)b * NN + jg) * CQ + q * 8);

    float a0 = 0.f, a1 = 0.f, a2 = 0.f, a3 = 0.f;
    float b0 = 0.f, b1 = 0.f, b2 = 0.f, b3 = 0.f;
    const f32x4 zero = {0.f, 0.f, 0.f, 0.f};

    half8 aA = *(const half8*)(const void*)(fbase + (size_t)col * CQ + q * 8);
    half8 aB = *(const half8*)(const void*)(fbase + (size_t)(16 + col) * CQ + q * 8);
    for (int i0 = 0; i0 < NN; i0 += 32) {
        int i_n = (i0 + 32) & (NN - 1);
        half8 aA2 = *(const half8*)(const void*)(fbase + (size_t)(i_n + col) * CQ + q * 8);
        half8 aB2 = *(const half8*)(const void*)(fbase + (size_t)(i_n + 16 + col) * CQ + q * 8);
        f32x4 d0 = __builtin_amdgcn_mfma_f32_16x16x32_f16(aA, gfrag, zero, 0, 0, 0);
        f32x4 d1 = __builtin_amdgcn_mfma_f32_16x16x32_f16(aB, gfrag, zero, 0, 0, 0);
        a0 += fexp2(d0[0]); a1 += fexp2(d0[1]); a2 += fexp2(d0[2]); a3 += fexp2(d0[3]);
        b0 += fexp2(d1[0]); b1 += fexp2(d1[1]); b2 += fexp2(d1[2]); b3 += fexp2(d1[3]);
        aA = aA2; aB = aB2;
    }
    float l = ((a0 + a1) + (a2 + a3)) + ((b0 + b1) + (b2 + b3));
    l += __shfl_xor(l, 16);
    l += __shfl_xor(l, 32);
    if (q == 0)
        linv[(size_t)b * NN + jg] = 1.f / l;
}

// --------------------------------------------------------------------------
// K3b: out = x (pass2 atomically accumulates partial O on top).
// --------------------------------------------------------------------------
__global__ __launch_bounds__(256) void initout_kernel(
    const float* __restrict__ x, float* __restrict__ out)
{
    size_t i = ((size_t)blockIdx.x * 256 + threadIdx.x) * 4;
    f32x4 v = __builtin_nontemporal_load((const f32x4*)(x + i));
    __builtin_nontemporal_store(v, (f32x4*)(out + i));
}

// --------------------------------------------------------------------------
// K4: partial O = h @ P^T over a j-half, atomicAdd into out.
// Block: 64 i x 128 c x 2048 j (4 waves x 32c), j-step 64.
// 1D grid 2048: b = gid&7 (XCD L2 affinity), (it 0..63, ch 0..1, jh 0..1).
// 8 blocks/CU (launch_bounds(256,8), 16KB LDS).  P = exp2(S')*linv: one exp
// + one mul per element.  XOR-swizzled P (b64 writes / b128 reads at bank
// floor).  g/linv prefetched one step ahead.
// --------------------------------------------------------------------------
__global__ __launch_bounds__(256, 8) void pass2_kernel(
    const __half* __restrict__ ft, const __half* __restrict__ gt,
    const __half* __restrict__ hm, const float* __restrict__ linv,
    float* __restrict__ out)
{
    const int tid = threadIdx.x;
    const int w = tid >> 6, lane = tid & 63, col = lane & 15, q = lane >> 4;
    const int gid = blockIdx.x;
    const int b  = gid & 7;
    const int r2 = gid >> 3;                 // 0..255
    const int i0 = (r2 & 63) * 64;
    const int cb = ((r2 >> 6) & 1) * 128 + 32 * w;
    const int J  = ((r2 >> 7) & 1) * 2048;   // j-half base

    __shared__ __half P[2][64 * 64];

    const __half* gbase = gt + (size_t)b * NN * CQ;
    const __half* hbase = hm + (size_t)b * CC * NN;
    const float*  lb    = linv + (size_t)b * NN;

    // loop-invariant f B-frags (n = i)
    half8 ffr[4];
#pragma unroll
    for (int it = 0; it < 4; ++it)
        ffr[it] = *(const half8*)(const void*)(ft + ((size_t)b * NN + i0 + 16 * it + col) * CQ + q * 8);

    f32x4 acc[4][2];
#pragma unroll
    for (int ms = 0; ms < 4; ++ms)
#pragma unroll
        for (int ns = 0; ns < 2; ++ns)
            acc[ms][ns] = (f32x4){0.f, 0.f, 0.f, 0.f};

    const f32x4 zero = {0.f, 0.f, 0.f, 0.f};
    const int jml = 16 * w + 4 * q;          // lane's j offset in the step
    const int sw  = 8 * (col & 7);           // P bank swizzle

    // prologue prefetch (step 0 of this j-half)
    half8  gfr = *(const half8*)(const void*)(gbase + (size_t)(J + 16 * w + col) * CQ + q * 8);
    float4 il  = *(const float4*)(lb + J + jml);

    int buf = 0;
    for (int jo = 0; jo < 2048; jo += 64, buf ^= 1) {
        const int j0 = J + jo;
        // current-step O-phase B-frags (L2-resident hm)
        half8 hv[2][2];
#pragma unroll
        for (int ns = 0; ns < 2; ++ns)
#pragma unroll
            for (int ks = 0; ks < 2; ++ks)
                hv[ns][ks] = *(const half8*)(const void*)(
                    hbase + (size_t)(cb + 16 * ns + col) * NN + j0 + ks * 32 + q * 8);

        // S'^T tiles: rows j = j0+16w+4q+r, cols i = 16it+col
        f32x4 d[4];
#pragma unroll
        for (int it = 0; it < 4; ++it)
            d[it] = __builtin_amdgcn_mfma_f32_16x16x32_f16(gfr, ffr[it], zero, 0, 0, 0);

        // next-step prefetch (wraps within the j-half on last iter)
        const int jn = J + ((jo + 64) & 2047);
        half8  gfr_n = *(const half8*)(const void*)(gbase + (size_t)(jn + 16 * w + col) * CQ + q * 8);
        float4 il_n  = *(const float4*)(lb + jn + jml);

        // P = exp2(S') * linv  -> swizzled LDS
        __half* Pb = &P[buf][0];
#pragma unroll
        for (int it = 0; it < 4; ++it) {
            half4v pv;
            pv[0] = (_Float16)(fexp2(d[it][0]) * il.x);
            pv[1] = (_Float16)(fexp2(d[it][1]) * il.y);
            pv[2] = (_Float16)(fexp2(d[it][2]) * il.z);
            pv[3] = (_Float16)(fexp2(d[it][3]) * il.w);
            *(half4v*)(void*)(Pb + (16 * it + col) * 64 + (jml ^ sw)) = pv;
        }
        __syncthreads();

        // O: A = P (swizzled b128 reads), B = hv
#pragma unroll
        for (int ks = 0; ks < 2; ++ks) {
            half8 af[4];
#pragma unroll
            for (int ms = 0; ms < 4; ++ms)
                af[ms] = *(const half8*)(const void*)(
                    Pb + (16 * ms + col) * 64 + ((ks * 32 + q * 8) ^ sw));
#pragma unroll
            for (int ms = 0; ms < 4; ++ms)
#pragma unroll
                for (int ns = 0; ns < 2; ++ns)
                    acc[ms][ns] = __builtin_amdgcn_mfma_f32_16x16x32_f16(
                        af[ms], hv[ns][ks], acc[ms][ns], 0, 0, 0);
        }
        gfr = gfr_n;
        il  = il_n;
    }

    // epilogue: atomic accumulate partial O into out (= x + sum of halves)
    float* ob = out + (size_t)b * CC * NN;
#pragma unroll
    for (int ms = 0; ms < 4; ++ms) {
#pragma unroll
        for (int ns = 0; ns < 2; ++ns) {
            int c  = cb + 16 * ns + col;
            int ii = i0 + 16 * ms + 4 * q;
            float* p = ob + (size_t)c * NN + ii;
            unsafeAtomicAdd(p + 0, acc[ms][ns][0]);
            unsafeAtomicAdd(p + 1, acc[ms][ns][1]);
            unsafeAtomicAdd(p + 2, acc[ms][ns][2]);
            unsafeAtomicAdd(p + 3, acc[ms][ns][3]);
        }
    }
}

// ---------------------------------------------------------------------------
extern "C" void kernel_launch(void* const* d_in, const int* in_sizes, int n_in,
                              void* d_out, int out_size, void* d_ws, size_t ws_size,
                              hipStream_t stream)
{
    const float* x  = (const float*)d_in[0];
    const float* fw = (const float*)d_in[1];
    const float* fb = (const float*)d_in[2];
    const float* gw = (const float*)d_in[3];
    const float* gb = (const float*)d_in[4];
    const float* hw = (const float*)d_in[5];
    const float* hb = (const float*)d_in[6];
    float* out = (float*)d_out;

    char* ws = (char*)d_ws;
    __half* xt = (__half*)(ws);                          // 16,777,216
    __half* wf = (__half*)(ws + (size_t)16777216);       //    163,840 (pad 256K)
    __half* ft = (__half*)(ws + (size_t)17039360);       //  2,097,152
    __half* gt = (__half*)(ws + (size_t)19136512);       //  2,097,152
    __half* hm = (__half*)(ws + (size_t)21233664);       // 16,777,216
    float*  lv = (float*) (ws + (size_t)38010880);       //    131,072

    cvtw_kernel<<<dim3(320), dim3(256), 0, stream>>>(fw, gw, hw, wf);
    transpose_kernel<<<dim3(2048), dim3(256), 0, stream>>>(x, xt);
    proj_kernel<<<dim3(2560), dim3(256), 0, stream>>>(xt, wf, fb, gb, hb, ft, gt, hm);
    pass1_kernel<<<dim3(512), dim3(256), 0, stream>>>(ft, gt, lv);
    initout_kernel<<<dim3(8192), dim3(256), 0, stream>>>(x, out);
    pass2_kernel<<<dim3(2048), dim3(256), 0, stream>>>(ft, gt, hm, lv, out);
}

// Round 6
// 487.863 us; speedup vs baseline: 1.9858x; 1.9858x over previous
//
#include <hip/hip_runtime.h>
#include <hip/hip_fp16.h>
#include <cmath>

// ---------------------------------------------------------------------------
// Self_Attention: B=8, C=256, C_=32, H=W=64, N=4096, GAMMA=1.0
// R6: barrier-free pass2. Per wave: private 16-j strip; S^T via 16x16x32
// (A=g, B=f) -> D[j][i] whose layout IS the B-operand layout of
// mfma_f32_16x16x16f16 -> P chains in-register into O-GEMM (A=h, b64 global).
// No LDS/barrier in the K-loop; one LDS reduction (ds_add_f32) at the end.
// pass1 i-quartered into partials (no atomics), tiny recip kernel.
// ws: xt 16M (l4 aliases it after proj) | wf | ft 2M | gt 2M | hm 16M | linv
// ---------------------------------------------------------------------------

#define BN 8
#define CC 256
#define CQ 32
#define NN 4096

typedef _Float16 half8 __attribute__((ext_vector_type(8)));
typedef _Float16 half4v __attribute__((ext_vector_type(4)));
typedef float f32x4 __attribute__((ext_vector_type(4)));

static __device__ __forceinline__ float fexp2(float x) {
    return __builtin_amdgcn_exp2f(x);
}

#define LOG2E 1.44269504f

// --------------------------------------------------------------------------
// K0: weight conversion f32 -> f16.
// --------------------------------------------------------------------------
__global__ __launch_bounds__(256) void cvtw_kernel(
    const float* __restrict__ fw, const float* __restrict__ gw,
    const float* __restrict__ hw, __half* __restrict__ wf16)
{
    int i = blockIdx.x * 256 + threadIdx.x;
    float v;
    if (i < 8192)       v = fw[i];
    else if (i < 16384) v = gw[i - 8192];
    else                v = hw[i - 16384];
    wf16[i] = __float2half(v);
}

// --------------------------------------------------------------------------
// K1: transpose + cvt x[b][c][n] f32 -> xt[b][n][c] f16.  64n x 64c tiles.
// --------------------------------------------------------------------------
__global__ __launch_bounds__(256) void transpose_kernel(
    const float* __restrict__ x, __half* __restrict__ xt)
{
    const int gid = blockIdx.x;
    const int b = gid & 7, rest = gid >> 3;
    const int n0 = (rest & 63) * 64;
    const int c0 = (rest >> 6) * 64;
    const int tid = threadIdx.x;

    __shared__ float T[64 * 65];

    const float* xb = x + ((size_t)b * CC + c0) * NN + n0;
    const int u  = tid >> 4;
    const int n4 = (tid & 15) * 4;
#pragma unroll
    for (int r = 0; r < 4; ++r) {
        int c = r * 16 + u;
        f32x4 v = __builtin_nontemporal_load((const f32x4*)(xb + (size_t)c * NN + n4));
        T[c * 65 + n4 + 0] = v.x;
        T[c * 65 + n4 + 1] = v.y;
        T[c * 65 + n4 + 2] = v.z;
        T[c * 65 + n4 + 3] = v.w;
    }
    __syncthreads();

    const int lane = tid & 63, w = tid >> 6;
    const int n  = w * 16 + (lane >> 2);
    const int cc = (lane & 3) * 16;
    half8 o0, o1;
#pragma unroll
    for (int k = 0; k < 8; ++k) {
        o0[k] = (_Float16)T[(cc + k) * 65 + n];
        o1[k] = (_Float16)T[(cc + 8 + k) * 65 + n];
    }
    __half* dst = xt + ((size_t)b * NN + n0 + n) * CC + c0 + cc;
    *(half8*)(void*)dst = o0;
    *(half8*)(void*)(dst + 8) = o1;
}

// --------------------------------------------------------------------------
// K2: MFMA projections. 1D grid 2560: b = gid&7, then (nt 0..63, ot 0..4).
//   ot==0: f+g (f scaled by LOG2E).  ot>=1: h -> hm[c][n].
// --------------------------------------------------------------------------
__global__ __launch_bounds__(256) void proj_kernel(
    const __half* __restrict__ xt, const __half* __restrict__ wf16,
    const float* __restrict__ fb, const float* __restrict__ gb,
    const float* __restrict__ hb,
    __half* __restrict__ ft, __half* __restrict__ gt, __half* __restrict__ hm)
{
    const int tid = threadIdx.x;
    const int w = tid >> 6, lane = tid & 63, col = lane & 15, q = lane >> 4;
    const int gid = blockIdx.x;
    const int b = gid & 7, rest = gid >> 3;
    const int n0 = (rest & 63) * 64;
    const int ot = rest >> 6;

    const __half* xtb  = xt + (size_t)b * NN * CC;
    const __half* fw16 = wf16;
    const __half* gw16 = wf16 + 8192;
    const __half* hw16 = wf16 + 16384;

    f32x4 acc[4];
#pragma unroll
    for (int mt = 0; mt < 4; ++mt) acc[mt] = (f32x4){0.f, 0.f, 0.f, 0.f};

    if (ot == 0) {
        const int pix = n0 + 16 * w + col;
#pragma unroll
        for (int ks = 0; ks < 8; ++ks) {
            half8 bf = *(const half8*)(const void*)(xtb + (size_t)pix * CC + ks * 32 + q * 8);
#pragma unroll
            for (int mt = 0; mt < 4; ++mt) {
                const __half* wp = (mt < 2) ? (fw16 + (16 * mt + col) * CC)
                                            : (gw16 + (16 * (mt - 2) + col) * CC);
                half8 af = *(const half8*)(const void*)(wp + ks * 32 + q * 8);
                acc[mt] = __builtin_amdgcn_mfma_f32_16x16x32_f16(af, bf, acc[mt], 0, 0, 0);
            }
        }
#pragma unroll
        for (int mt = 0; mt < 4; ++mt) {
            const int mtl = mt & 1;
            const float* bsel = (mt < 2) ? fb : gb;
            const float scale = (mt < 2) ? LOG2E : 1.0f;
            __half* dsel = (mt < 2) ? ft : gt;
            half4v hv;
#pragma unroll
            for (int r = 0; r < 4; ++r)
                hv[r] = (_Float16)((acc[mt][r] + bsel[16 * mtl + 4 * q + r]) * scale);
            *(half4v*)(void*)(dsel + ((size_t)b * NN + pix) * CQ + 16 * mtl + 4 * q) = hv;
        }
    } else {
        const int c = (ot - 1) * 64 + 16 * w + col;
#pragma unroll
        for (int ks = 0; ks < 8; ++ks) {
            half8 bf = *(const half8*)(const void*)(hw16 + (size_t)c * CC + ks * 32 + q * 8);
#pragma unroll
            for (int mt = 0; mt < 4; ++mt) {
                half8 af = *(const half8*)(const void*)(xtb + (size_t)(n0 + 16 * mt + col) * CC + ks * 32 + q * 8);
                acc[mt] = __builtin_amdgcn_mfma_f32_16x16x32_f16(af, bf, acc[mt], 0, 0, 0);
            }
        }
        const float bias = hb[c];
#pragma unroll
        for (int mt = 0; mt < 4; ++mt) {
            half4v hv;
#pragma unroll
            for (int r = 0; r < 4; ++r)
                hv[r] = (_Float16)(acc[mt][r] + bias);
            *(half4v*)(void*)(hm + ((size_t)b * CC + c) * NN + n0 + 16 * mt + 4 * q) = hv;
        }
    }
}

// --------------------------------------------------------------------------
// K3: partial softmax denominators over an i-quarter (1024 i).
// 1D grid 2048: b = gid&7, jt = (gid>>3)&63, part = gid>>9.  No atomics:
// l4[part][b][j] partials, combined by linv_kernel.
// --------------------------------------------------------------------------
__global__ __launch_bounds__(256) void pass1_kernel(
    const __half* __restrict__ ft, const __half* __restrict__ gt,
    float* __restrict__ l4)
{
    const int tid = threadIdx.x;
    const int w = tid >> 6, lane = tid & 63, col = lane & 15, q = lane >> 4;
    const int gid = blockIdx.x;
    const int b = gid & 7;
    const int jg = ((gid >> 3) & 63) * 64 + 16 * w + col;
    const int part = gid >> 9;
    const int ib = part * 1024;

    const __half* fbase = ft + (size_t)b * NN * CQ;
    half8 gfrag = *(const half8*)(const void*)(gt + ((size_t)b * NN + jg) * CQ + q * 8);

    float a0 = 0.f, a1 = 0.f, a2 = 0.f, a3 = 0.f;
    float b0 = 0.f, b1 = 0.f, b2 = 0.f, b3 = 0.f;
    const f32x4 zero = {0.f, 0.f, 0.f, 0.f};

    half8 aA = *(const half8*)(const void*)(fbase + (size_t)(ib + col) * CQ + q * 8);
    half8 aB = *(const half8*)(const void*)(fbase + (size_t)(ib + 16 + col) * CQ + q * 8);
    for (int i0 = ib; i0 < ib + 1024; i0 += 32) {
        int i_n = (i0 + 32) & (NN - 1);
        half8 aA2 = *(const half8*)(const void*)(fbase + (size_t)(i_n + col) * CQ + q * 8);
        half8 aB2 = *(const half8*)(const void*)(fbase + (size_t)(i_n + 16 + col) * CQ + q * 8);
        f32x4 d0 = __builtin_amdgcn_mfma_f32_16x16x32_f16(aA, gfrag, zero, 0, 0, 0);
        f32x4 d1 = __builtin_amdgcn_mfma_f32_16x16x32_f16(aB, gfrag, zero, 0, 0, 0);
        a0 += fexp2(d0[0]); a1 += fexp2(d0[1]); a2 += fexp2(d0[2]); a3 += fexp2(d0[3]);
        b0 += fexp2(d1[0]); b1 += fexp2(d1[1]); b2 += fexp2(d1[2]); b3 += fexp2(d1[3]);
        aA = aA2; aB = aB2;
    }
    float l = ((a0 + a1) + (a2 + a3)) + ((b0 + b1) + (b2 + b3));
    l += __shfl_xor(l, 16);
    l += __shfl_xor(l, 32);
    if (q == 0)
        l4[(size_t)part * (BN * NN) + (size_t)b * NN + jg] = l;
}

// --------------------------------------------------------------------------
// K3b: linv = 1 / (sum of 4 partials).  32768 elems, 128 blocks.
// --------------------------------------------------------------------------
__global__ __launch_bounds__(256) void linv_kernel(
    const float* __restrict__ l4, float* __restrict__ linv)
{
    int i = blockIdx.x * 256 + threadIdx.x;
    float s = l4[i] + l4[BN * NN + i] + l4[2 * BN * NN + i] + l4[3 * BN * NN + i];
    linv[i] = 1.f / s;
}

// --------------------------------------------------------------------------
// K4: O = h @ P^T + x, barrier-free K-loop.
// 1D grid 2048: b=gid&7, it=(gid>>3)&63 -> i0, cq=gid>>9 -> cb (64 c).
// Wave w owns j strips {64s+16w}. Per step:
//   S^T: D[j][i] = mfma_16x16x32(A=g, B=f)  (4 i-tiles)
//   P = exp2(S')*linv -> half4 pv, register-chained as B-operand of
//   O: acc += mfma_16x16x16f16(A=h b64 global, B=pv)  (4 c-tiles)
// End: 4-wave j-quarter reduction in LDS (wave0 store, ds_add_f32), +x, out.
// --------------------------------------------------------------------------
__global__ __launch_bounds__(256) void pass2_kernel(
    const float* __restrict__ x,
    const __half* __restrict__ ft, const __half* __restrict__ gt,
    const __half* __restrict__ hm, const float* __restrict__ linv,
    float* __restrict__ out)
{
    const int tid = threadIdx.x;
    const int w = tid >> 6, lane = tid & 63, col = lane & 15, q = lane >> 4;
    const int gid = blockIdx.x;
    const int b  = gid & 7;
    const int r2 = gid >> 3;                 // 0..255
    const int i0 = (r2 & 63) * 64;
    const int cb = (r2 >> 6) * 64;

    __shared__ float red[64 * 68];           // [c][i], pitch 68 (16B-aligned rows)

    const __half* gbase = gt + (size_t)b * NN * CQ;
    const __half* hbase = hm + (size_t)b * CC * NN;
    const float*  lb    = linv + (size_t)b * NN;

    // loop-invariant f B-frags (n = i)
    half8 ffr[4];
#pragma unroll
    for (int it = 0; it < 4; ++it)
        ffr[it] = *(const half8*)(const void*)(ft + ((size_t)b * NN + i0 + 16 * it + col) * CQ + q * 8);

    f32x4 acc[4][4];                         // [it][ct]
#pragma unroll
    for (int it = 0; it < 4; ++it)
#pragma unroll
        for (int ct = 0; ct < 4; ++ct)
            acc[it][ct] = (f32x4){0.f, 0.f, 0.f, 0.f};

    const f32x4 zero = {0.f, 0.f, 0.f, 0.f};

    // prologue prefetch: strip s=0 -> jstrip = 16w
    half8  gfr = *(const half8*)(const void*)(gbase + (size_t)(16 * w + col) * CQ + q * 8);
    float4 ilv = *(const float4*)(lb + 16 * w + 4 * q);

    for (int s = 0; s < 64; ++s) {
        const int jstrip = 64 * s + 16 * w;

        // h A-frags for this strip: A[m=c][k=j] -> b64 at hm[c][jstrip+4q]
        half4v hfr[4];
#pragma unroll
        for (int ct = 0; ct < 4; ++ct)
            hfr[ct] = *(const half4v*)(const void*)(
                hbase + (size_t)(cb + 16 * ct + col) * NN + jstrip + 4 * q);

        // S^T: D[j=4q+r][i=16it+col]
        f32x4 d[4];
#pragma unroll
        for (int it = 0; it < 4; ++it)
            d[it] = __builtin_amdgcn_mfma_f32_16x16x32_f16(gfr, ffr[it], zero, 0, 0, 0);

        // next-strip prefetch (wraps harmlessly)
        const int jn = 64 * ((s + 1) & 63) + 16 * w;
        half8  gfr_n = *(const half8*)(const void*)(gbase + (size_t)(jn + col) * CQ + q * 8);
        float4 ilv_n = *(const float4*)(lb + jn + 4 * q);

        // P chain: D-layout == B-operand layout of 16x16x16
#pragma unroll
        for (int it = 0; it < 4; ++it) {
            half4v pv;
            pv[0] = (_Float16)(fexp2(d[it][0]) * ilv.x);
            pv[1] = (_Float16)(fexp2(d[it][1]) * ilv.y);
            pv[2] = (_Float16)(fexp2(d[it][2]) * ilv.z);
            pv[3] = (_Float16)(fexp2(d[it][3]) * ilv.w);
#pragma unroll
            for (int ct = 0; ct < 4; ++ct)
                acc[it][ct] = __builtin_amdgcn_mfma_f32_16x16x16f16(
                    hfr[ct], pv, acc[it][ct], 0, 0, 0);
        }
        gfr = gfr_n;
        ilv = ilv_n;
    }

    // ---- cross-wave j-quarter reduction ----
    // D of O-GEMM: lane holds O[c = 16ct+4q+r][i = 16it+col]
    if (w == 0) {
#pragma unroll
        for (int it = 0; it < 4; ++it)
#pragma unroll
            for (int ct = 0; ct < 4; ++ct)
#pragma unroll
                for (int r = 0; r < 4; ++r)
                    red[(16 * ct + 4 * q + r) * 68 + 16 * it + col] = acc[it][ct][r];
    }
    __syncthreads();
    if (w != 0) {
#pragma unroll
        for (int it = 0; it < 4; ++it)
#pragma unroll
            for (int ct = 0; ct < 4; ++ct)
#pragma unroll
                for (int r = 0; r < 4; ++r)
                    atomicAdd(&red[(16 * ct + 4 * q + r) * 68 + 16 * it + col],
                              acc[it][ct][r]);
    }
    __syncthreads();

    // coalesced +x store: thread -> 4 rows of 4 floats
    const int cr = tid >> 4;                 // 0..15
    const int i4 = (tid & 15) * 4;
#pragma unroll
    for (int k = 0; k < 4; ++k) {
        int c = cr + 16 * k;
        size_t off = (size_t)(b * CC + cb + c) * NN + i0 + i4;
        f32x4 v = *(const f32x4*)&red[c * 68 + i4];
        f32x4 xv = __builtin_nontemporal_load((const f32x4*)(x + off));
        v.x += xv.x; v.y += xv.y; v.z += xv.z; v.w += xv.w;
        __builtin_nontemporal_store(v, (f32x4*)(out + off));
    }
}

// ---------------------------------------------------------------------------
extern "C" void kernel_launch(void* const* d_in, const int* in_sizes, int n_in,
                              void* d_out, int out_size, void* d_ws, size_t ws_size,
                              hipStream_t stream)
{
    const float* x  = (const float*)d_in[0];
    const float* fw = (const float*)d_in[1];
    const float* fb = (const float*)d_in[2];
    const float* gw = (const float*)d_in[3];
    const float* gb = (const float*)d_in[4];
    const float* hw = (const float*)d_in[5];
    const float* hb = (const float*)d_in[6];
    float* out = (float*)d_out;

    char* ws = (char*)d_ws;
    __half* xt = (__half*)(ws);                          // 16 MB (dead after proj)
    float*  l4 = (float*)(ws);                           // aliases xt: 512 KB
    __half* wf = (__half*)(ws + (size_t)16777216);
    __half* ft = (__half*)(ws + (size_t)17039360);
    __half* gt = (__half*)(ws + (size_t)19136512);
    __half* hm = (__half*)(ws + (size_t)21233664);
    float*  lv = (float*) (ws + (size_t)38010880);

    cvtw_kernel<<<dim3(320), dim3(256), 0, stream>>>(fw, gw, hw, wf);
    transpose_kernel<<<dim3(2048), dim3(256), 0, stream>>>(x, xt);
    proj_kernel<<<dim3(2560), dim3(256), 0, stream>>>(xt, wf, fb, gb, hb, ft, gt, hm);
    pass1_kernel<<<dim3(2048), dim3(256), 0, stream>>>(ft, gt, l4);
    linv_kernel<<<dim3(128), dim3(256), 0, stream>>>(l4, lv);
    pass2_kernel<<<dim3(2048), dim3(256), 0, stream>>>(x, ft, gt, hm, lv, out);
}